// Round 1
// baseline (1133.747 us; speedup 1.0000x reference)
//
#include <hip/hip_runtime.h>
#include <math.h>

// Swin shifted-window attention, fully fused, fp32.
// One block per (batch, window): 16*256 = 4096 blocks, 512 threads.
//
// LDS pool layout (floats):
//   OFF_XS  [64][132]  x window (phase 0-1), reused as O (attn out) phase 2-3
//   OFF_QT  [128][68]  q transposed [chan][tok]; reused (with KT) as w_out stage in phase 3
//   OFF_KT  [128][68]  k transposed
//   OFF_V   [64][130]  v [tok][chan]
//   OFF_WB  [384][10]  w_qkv k-chunk stage; reused as ST [64][66] (P transposed) in phase 2
//   OFF_PE  [225]      pos_emb
// total 38640 floats = 154560 B  (<= 160 KiB gfx950 LDS) -> 1 block/CU, 8 waves/CU

#define IMG 128
#define CH  128
#define DISP 4

#define XS_S 132
#define QT_S 68
#define V_S  130
#define WB_S 10
#define ST_S 66
#define WO_S 130

#define OFF_XS 0
#define OFF_QT 8448
#define OFF_KT 17152
#define OFF_V  25856
#define OFF_WB 34176
#define OFF_PE 38400
#define POOL_N 38640

__global__ __launch_bounds__(512)
void swin_window_attn(const float* __restrict__ x,
                      const float* __restrict__ w_qkv,
                      const float* __restrict__ w_out,
                      const float* __restrict__ b_out,
                      const float* __restrict__ pos_emb,
                      float* __restrict__ out)
{
    __shared__ float lds[POOL_N];
    float* xs = lds + OFF_XS;   // [64][XS_S]
    float* Ob = lds + OFF_XS;   // alias (phase 2-3)
    float* qT = lds + OFF_QT;   // [128][QT_S]
    float* kT = lds + OFF_KT;   // [128][QT_S]
    float* vb = lds + OFF_V;    // [64][V_S]
    float* wb = lds + OFF_WB;   // [384][WB_S]
    float* st = lds + OFF_WB;   // alias: [64][ST_S]
    float* wo = lds + OFF_QT;   // alias: [128][WO_S] (phase 3)
    float* pe = lds + OFF_PE;   // [225]

    const int t   = threadIdx.x;
    const int bid = blockIdx.x;
    const int bi  = bid >> 8;
    const int wy  = (bid >> 4) & 15;
    const int wx  = bid & 15;
    const int tx  = t & 63;
    const int ty  = t >> 6;

    // ---------------- phase 0: load shifted x window + pos_emb ----------------
    {
        const float* xb = x + (size_t)bi * (IMG * IMG * CH);
        #pragma unroll
        for (int it = 0; it < 4; ++it) {
            int idx = t + it * 512;          // 2048 float4 = 64 tok x 128 ch
            int tok = idx >> 5;
            int f4  = (idx & 31) << 2;
            int gr = ((wy << 3) + (tok >> 3) + DISP) & 127;  // roll(-DISP): read x[i+4]
            int gc = ((wx << 3) + (tok & 7) + DISP) & 127;
            float4 v4 = *(const float4*)(xb + (gr * IMG + gc) * CH + f4);
            *(float4*)(xs + tok * XS_S + f4) = v4;
        }
        if (t < 225) pe[t] = pos_emb[t];
    }
    __syncthreads();

    // ---------------- phase 1: qkv = xs @ w_qkv^T ----------------
    // thread (ty 0..7, tx 0..63): tokens ty*8..ty*8+7, out channels tx + 64*j (j=0..5)
    // j=0,1 -> q(0..127), j=2,3 -> k(128..255), j=4,5 -> v(256..383)
    float acc[8][6];
    #pragma unroll
    for (int i = 0; i < 8; ++i)
        #pragma unroll
        for (int j = 0; j < 6; ++j) acc[i][j] = 0.f;

    for (int k0 = 0; k0 < 128; k0 += 8) {
        // stage wb[o][kk] = w_qkv[o][k0+kk], 384x8 floats
        #pragma unroll
        for (int it = 0; it < 3; ++it) {
            int idx = t + it * 512;          // 1536 float2
            int o   = idx >> 2;
            int kp  = (idx & 3) << 1;
            float2 wv = *(const float2*)(w_qkv + o * CH + k0 + kp);
            *(float2*)(wb + o * WB_S + kp) = wv;
        }
        __syncthreads();
        #pragma unroll
        for (int kk = 0; kk < 8; kk += 2) {
            float2 xv[8], wv[6];
            #pragma unroll
            for (int i = 0; i < 8; ++i)     // wave-broadcast reads
                xv[i] = *(const float2*)(xs + (ty * 8 + i) * XS_S + k0 + kk);
            #pragma unroll
            for (int j = 0; j < 6; ++j)     // stride-10 rows: 2-way max
                wv[j] = *(const float2*)(wb + (tx + 64 * j) * WB_S + kk);
            #pragma unroll
            for (int i = 0; i < 8; ++i)
                #pragma unroll
                for (int j = 0; j < 6; ++j)
                    acc[i][j] += xv[i].x * wv[j].x + xv[i].y * wv[j].y;
        }
        __syncthreads();
    }

    // write q,k transposed [chan][tok]; v as [tok][chan]
    #pragma unroll
    for (int j = 0; j < 2; ++j) {
        float* dst = qT + (tx + 64 * j) * QT_S + ty * 8;
        *(float4*)(dst)     = make_float4(acc[0][j], acc[1][j], acc[2][j], acc[3][j]);
        *(float4*)(dst + 4) = make_float4(acc[4][j], acc[5][j], acc[6][j], acc[7][j]);
    }
    #pragma unroll
    for (int j = 2; j < 4; ++j) {
        float* dst = kT + (tx + 64 * (j - 2)) * QT_S + ty * 8;
        *(float4*)(dst)     = make_float4(acc[0][j], acc[1][j], acc[2][j], acc[3][j]);
        *(float4*)(dst + 4) = make_float4(acc[4][j], acc[5][j], acc[6][j], acc[7][j]);
    }
    #pragma unroll
    for (int j = 4; j < 6; ++j)
        #pragma unroll
        for (int i = 0; i < 8; ++i)
            vb[(ty * 8 + i) * V_S + tx + 64 * (j - 4)] = acc[i][j];
    __syncthreads();

    // ---------------- normalize q (fold in 1/TAU = 50) and k ----------------
    // 512 units: (qk = t>>8, head = (t>>6)&3, tok = t&63)
    {
        int i = t & 63;
        int h = (t >> 6) & 3;
        float* base = ((t >> 8) ? kT : qT) + (h * 32) * QT_S + i;
        float s = 0.f;
        #pragma unroll
        for (int d = 0; d < 32; ++d) { float v = base[d * QT_S]; s += v * v; }
        float scale = ((t >> 8) ? 1.0f : 50.0f) / fmaxf(sqrtf(s), 1e-12f);
        #pragma unroll
        for (int d = 0; d < 32; ++d) base[d * QT_S] *= scale;
    }
    __syncthreads();

    // ---------------- bias (+shift mask) for this thread's score tile ----------------
    // scores map: thread (ig = t>>4 in 0..31, jg = t&15): rows {2ig,2ig+1}, cols {4jg..4jg+3}
    const int jg = t & 15;
    const int ig = t >> 4;
    float bias[2][4];
    #pragma unroll
    for (int a = 0; a < 2; ++a) {
        int i  = 2 * ig + a;
        int ri = i >> 3, ci = i & 7;
        #pragma unroll
        for (int b = 0; b < 4; ++b) {
            int j  = 4 * jg + b;
            int rj = j >> 3, cj = j & 7;
            float bv = pe[(rj - ri + 7) * 15 + (cj - ci + 7)];  // REL = idx[j]-idx[i]
            bool masked = ((wy == 15) && ((i >= 32) != (j >= 32)))     // TB mask, last window row
                       || ((wx == 15) && ((ci >= 4) != (cj >= 4)));    // LR mask, last window col
            bias[a][b] = masked ? -1e30f : bv;
        }
    }

    // ---------------- phase 2: per-head attention ----------------
    for (int h = 0; h < 4; ++h) {
        float s[2][4];
        #pragma unroll
        for (int a = 0; a < 2; ++a)
            #pragma unroll
            for (int b = 0; b < 4; ++b) s[a][b] = bias[a][b];
        const float* qp = qT + (h * 32) * QT_S + 2 * ig;
        const float* kp = kT + (h * 32) * QT_S + 4 * jg;
        #pragma unroll
        for (int d = 0; d < 32; ++d) {
            float2 qv = *(const float2*)(qp + d * QT_S);
            float4 kv = *(const float4*)(kp + d * QT_S);
            s[0][0] += qv.x * kv.x; s[0][1] += qv.x * kv.y;
            s[0][2] += qv.x * kv.z; s[0][3] += qv.x * kv.w;
            s[1][0] += qv.y * kv.x; s[1][1] += qv.y * kv.y;
            s[1][2] += qv.y * kv.z; s[1][3] += qv.y * kv.w;
        }

        // softmax over j (row lives in 16 consecutive lanes)
        float p[2][4];
        #pragma unroll
        for (int a = 0; a < 2; ++a) {
            float m = fmaxf(fmaxf(s[a][0], s[a][1]), fmaxf(s[a][2], s[a][3]));
            #pragma unroll
            for (int off = 1; off < 16; off <<= 1)
                m = fmaxf(m, __shfl_xor(m, off, 16));
            float e0 = __expf(s[a][0] - m);
            float e1 = __expf(s[a][1] - m);
            float e2 = __expf(s[a][2] - m);
            float e3 = __expf(s[a][3] - m);
            float sum = (e0 + e1) + (e2 + e3);
            #pragma unroll
            for (int off = 1; off < 16; off <<= 1)
                sum += __shfl_xor(sum, off, 16);
            float inv = 1.0f / sum;
            p[a][0] = e0 * inv; p[a][1] = e1 * inv;
            p[a][2] = e2 * inv; p[a][3] = e3 * inv;
        }
        #pragma unroll
        for (int b = 0; b < 4; ++b)  // ST[j][i] (transposed P)
            *(float2*)(st + (4 * jg + b) * ST_S + 2 * ig) = make_float2(p[0][b], p[1][b]);
        __syncthreads();

        // PV: thread (ig, dg=jg): rows {2ig,2ig+1}, dims {2dg,2dg+1}
        {
            const int dg = jg;
            const float* vp = vb + h * 32 + 2 * dg;
            const float* sp = st + 2 * ig;
            float o00 = 0.f, o01 = 0.f, o10 = 0.f, o11 = 0.f;
            #pragma unroll 16
            for (int j = 0; j < 64; ++j) {
                float2 pv = *(const float2*)(sp + j * ST_S);   // broadcast
                float2 vv = *(const float2*)(vp + j * V_S);    // conflict-free
                o00 += pv.x * vv.x; o01 += pv.x * vv.y;
                o10 += pv.y * vv.x; o11 += pv.y * vv.y;
            }
            *(float2*)(Ob + (2 * ig)     * XS_S + h * 32 + 2 * dg) = make_float2(o00, o01);
            *(float2*)(Ob + (2 * ig + 1) * XS_S + h * 32 + 2 * dg) = make_float2(o10, o11);
        }
        __syncthreads();
    }

    // ---------------- phase 3: out = Ob @ w_out^T + b_out, reverse shift ----------------
    // stage w_out into wo[oc][k] (stride 130 -> 2-way max on reads)
    #pragma unroll
    for (int it = 0; it < 8; ++it) {
        int idx = t + it * 512;              // 4096 float4
        int oc  = idx >> 5;
        int k4  = (idx & 31) << 2;
        float4 w4 = *(const float4*)(w_out + oc * CH + k4);
        *(float2*)(wo + oc * WO_S + k4)     = make_float2(w4.x, w4.y);
        *(float2*)(wo + oc * WO_S + k4 + 2) = make_float2(w4.z, w4.w);
    }
    __syncthreads();

    float g[8][2];
    #pragma unroll
    for (int i = 0; i < 8; ++i) { g[i][0] = 0.f; g[i][1] = 0.f; }
    #pragma unroll 4
    for (int k = 0; k < 128; k += 2) {
        float2 ov[8], wv2[2];
        #pragma unroll
        for (int i = 0; i < 8; ++i)          // broadcast
            ov[i] = *(const float2*)(Ob + (ty * 8 + i) * XS_S + k);
        wv2[0] = *(const float2*)(wo + tx * WO_S + k);
        wv2[1] = *(const float2*)(wo + (tx + 64) * WO_S + k);
        #pragma unroll
        for (int i = 0; i < 8; ++i) {
            g[i][0] += ov[i].x * wv2[0].x + ov[i].y * wv2[0].y;
            g[i][1] += ov[i].x * wv2[1].x + ov[i].y * wv2[1].y;
        }
    }

    const float b0 = b_out[tx], b1 = b_out[tx + 64];
    float* ob = out + (size_t)bi * (IMG * IMG * CH);
    #pragma unroll
    for (int i = 0; i < 8; ++i) {
        int tok = ty * 8 + i;
        int gr = ((wy << 3) + (tok >> 3) + DISP) & 127;  // roll(+DISP): write to [i+4]
        int gc = ((wx << 3) + (tok & 7) + DISP) & 127;
        float* pdst = ob + (gr * IMG + gc) * CH;
        pdst[tx]      = g[i][0] + b0;
        pdst[tx + 64] = g[i][1] + b1;
    }
}

extern "C" void kernel_launch(void* const* d_in, const int* in_sizes, int n_in,
                              void* d_out, int out_size, void* d_ws, size_t ws_size,
                              hipStream_t stream) {
    const float* x       = (const float*)d_in[0];
    const float* w_qkv   = (const float*)d_in[1];
    const float* w_out   = (const float*)d_in[2];
    const float* b_out   = (const float*)d_in[3];
    const float* pos_emb = (const float*)d_in[4];
    float* outp = (float*)d_out;

    swin_window_attn<<<dim3(4096), dim3(512), 0, stream>>>(
        x, w_qkv, w_out, b_out, pos_emb, outp);
}

// Round 2
// 482.116 us; speedup vs baseline: 2.3516x; 2.3516x over previous
//
#include <hip/hip_runtime.h>
#include <math.h>

// Swin shifted-window attention, fully fused, MFMA (split-bf16 + f16 PV).
// One block per (batch, window): 4096 blocks x 512 threads (8 waves).
//
// GEMM plan (all MFMA 16x16x32):
//   QKV : C[64][384] = X[64][128] @ Wqkv^T      split-bf16 (3 mfma/tile-k)
//   QK^T: S[64][64]  = Qraw @ Kraw^T  (per head) split-bf16, norms folded in AFTER
//   PV  : O[64][32]  = P @ V          (per head) f16 single
//   proj: Y[64][128] = O[64][128] @ Wout^T       split-bf16
//
// D-fragment layout (m89-verified): col = lane&15, row = (lane>>4)*4 + reg.
// A-frag: lane reads A[row=lane&15][k=(lane>>4)*8 + 0..7] (contiguous 16B)
// B-frag: lane reads B^T-source row n=lane&15, k contiguous.

typedef short     bs8 __attribute__((ext_vector_type(8)));   // bf16 frag (4 VGPR)
typedef _Float16  hs8 __attribute__((ext_vector_type(8)));   // f16 frag
typedef float     f4_t __attribute__((ext_vector_type(4)));
typedef short     s4_t __attribute__((ext_vector_type(4)));
typedef _Float16  h4_t __attribute__((ext_vector_type(4)));

union B8 { s4_t s[2]; bs8 b; hs8 h; };

#define MFB(a,b,c) __builtin_amdgcn_mfma_f32_16x16x32_bf16(a,b,c,0,0,0)
#define MFH(a,b,c) __builtin_amdgcn_mfma_f32_16x16x32_f16(a,b,c,0,0,0)

// ---- LDS byte offsets (regions reused across phases; all 16B-aligned) ----
// Phase A (QKV):   XH/XL [64][136]bf16, WH/WL [192][136]bf16
// Phase B (attn):  QH/QL,KH/KL [4][64][36]bf16, VT [4][32][68]f16, P [4][64][68]f16,
//                  OH/OL [64][132]bf16
// Phase C (proj):  WOH/WOL [128][136]bf16 (overlays dead Q/K)
// Persistent:      PE (225 f32), SCL (512 f32 per-token norm scales)
#define XH_O   0
#define XL_O   17408
#define WH_O   34816
#define WL_O   87040
#define QH_O   0
#define QL_O   18432
#define KH_O   36864
#define KL_O   55296
#define VT_O   73728
#define P_O    91136
#define OH_O   125952
#define OL_O   142848
#define WOH_O  0
#define WOL_O  34816
#define PE_O   159744
#define SCL_O  160656
#define LDS_BYTES 162704

#define IMG 128
#define DISP 4

__device__ __forceinline__ unsigned short f2bf(float f) {
    unsigned u = __float_as_uint(f);
    return (unsigned short)((u + 0x7FFFu + ((u >> 16) & 1u)) >> 16);  // RNE
}
__device__ __forceinline__ float bf2f(unsigned short s) {
    return __uint_as_float(((unsigned)s) << 16);
}

__global__ __launch_bounds__(512, 2)
void swin_window_attn(const float* __restrict__ x,
                      const float* __restrict__ w_qkv,
                      const float* __restrict__ w_out,
                      const float* __restrict__ b_out,
                      const float* __restrict__ pos_emb,
                      float* __restrict__ out)
{
    __shared__ __align__(16) char LB[LDS_BYTES];
    #define PTR(off) (LB + (off))

    const int t   = threadIdx.x;
    const int bid = blockIdx.x;
    const int bi  = bid >> 8;
    const int wy  = (bid >> 4) & 15;
    const int wx  = bid & 15;
    const int l   = t & 63;
    const int wv  = t >> 6;
    const int li  = l & 15;
    const int lg  = l >> 4;

    // ---------------- phase 0: stage shifted X window (bf16 hi/lo) + pos_emb ----
    {
        const float* xb = x + (size_t)bi * (IMG * IMG * 128);
        #pragma unroll
        for (int it = 0; it < 4; ++it) {
            int idx = t + it * 512;            // 2048 float4
            int tok = idx >> 5;
            int f4  = (idx & 31) << 2;
            int gr = ((wy << 3) + (tok >> 3) + DISP) & 127;
            int gc = ((wx << 3) + (tok & 7) + DISP) & 127;
            float4 v4 = *(const float4*)(xb + (gr * IMG + gc) * 128 + f4);
            unsigned short h0 = f2bf(v4.x), h1 = f2bf(v4.y), h2 = f2bf(v4.z), h3 = f2bf(v4.w);
            s4_t hv = { (short)h0, (short)h1, (short)h2, (short)h3 };
            s4_t lv = { (short)f2bf(v4.x - bf2f(h0)), (short)f2bf(v4.y - bf2f(h1)),
                        (short)f2bf(v4.z - bf2f(h2)), (short)f2bf(v4.w - bf2f(h3)) };
            *(s4_t*)(PTR(XH_O) + (tok * 136 + f4) * 2) = hv;
            *(s4_t*)(PTR(XL_O) + (tok * 136 + f4) * 2) = lv;
        }
        if (t < 225) ((float*)PTR(PE_O))[t] = pos_emb[t];
    }
    __syncthreads();

    // ---------------- phase A: QKV = X @ Wqkv^T (two 192-channel halves) -------
    // wave -> 2 m-tiles x 3 n-tiles: mtp = wv>>2, ntq = wv&3
    const int mtp = wv >> 2;
    const int ntq = wv & 3;
    f4_t acc[12];
    #pragma unroll
    for (int i = 0; i < 12; ++i) acc[i] = (f4_t){0.f, 0.f, 0.f, 0.f};

    #pragma unroll
    for (int hf = 0; hf < 2; ++hf) {
        // stage Wqkv[hf*192 .. +192][128] as bf16 hi/lo
        #pragma unroll
        for (int it = 0; it < 12; ++it) {
            int idx = t + it * 512;            // 6144 float4
            int o   = idx >> 5;
            int f4  = (idx & 31) << 2;
            float4 v4 = *(const float4*)(w_qkv + (size_t)(hf * 192 + o) * 128 + f4);
            unsigned short h0 = f2bf(v4.x), h1 = f2bf(v4.y), h2 = f2bf(v4.z), h3 = f2bf(v4.w);
            s4_t hv = { (short)h0, (short)h1, (short)h2, (short)h3 };
            s4_t lv = { (short)f2bf(v4.x - bf2f(h0)), (short)f2bf(v4.y - bf2f(h1)),
                        (short)f2bf(v4.z - bf2f(h2)), (short)f2bf(v4.w - bf2f(h3)) };
            *(s4_t*)(PTR(WH_O) + (o * 136 + f4) * 2) = hv;
            *(s4_t*)(PTR(WL_O) + (o * 136 + f4) * 2) = lv;
        }
        __syncthreads();

        #pragma unroll
        for (int ks = 0; ks < 4; ++ks) {
            int koff = ks * 32 + lg * 8;
            bs8 ah[2], al[2];
            #pragma unroll
            for (int m = 0; m < 2; ++m) {
                int row = ((mtp * 2 + m) * 16 + li);
                ah[m] = *(const bs8*)(PTR(XH_O) + (row * 136 + koff) * 2);
                al[m] = *(const bs8*)(PTR(XL_O) + (row * 136 + koff) * 2);
            }
            #pragma unroll
            for (int j = 0; j < 3; ++j) {
                int wrow = (ntq * 3 + j) * 16 + li;
                bs8 bh = *(const bs8*)(PTR(WH_O) + (wrow * 136 + koff) * 2);
                bs8 bl = *(const bs8*)(PTR(WL_O) + (wrow * 136 + koff) * 2);
                #pragma unroll
                for (int m = 0; m < 2; ++m) {
                    int ai = hf * 6 + j * 2 + m;
                    acc[ai] = MFB(ah[m], bh, acc[ai]);
                    acc[ai] = MFB(ah[m], bl, acc[ai]);
                    acc[ai] = MFB(al[m], bh, acc[ai]);
                }
            }
        }
        __syncthreads();   // before restaging W (hf=0) / before output writes (hf=1)
    }

    // ---------------- distribute QKV: raw-split q/k, f16 V^T -------------------
    #pragma unroll
    for (int hf = 0; hf < 2; ++hf)
        #pragma unroll
        for (int j = 0; j < 3; ++j)
            #pragma unroll
            for (int m = 0; m < 2; ++m) {
                int ch   = hf * 192 + (ntq * 3 + j) * 16 + li;
                int tokb = (mtp * 2 + m) * 16 + lg * 4;
                f4_t vv  = acc[hf * 6 + j * 2 + m];
                if (ch < 256) {                               // q or k (wave-uniform)
                    int isK = ch >> 7;
                    int hh  = (ch >> 5) & 3;
                    int d   = ch & 31;
                    char* ph = PTR(isK ? KH_O : QH_O) + ((hh * 64 + tokb) * 36 + d) * 2;
                    char* pl = PTR(isK ? KL_O : QL_O) + ((hh * 64 + tokb) * 36 + d) * 2;
                    #pragma unroll
                    for (int r = 0; r < 4; ++r) {
                        float q = vv[r];
                        unsigned short hi = f2bf(q);
                        *(short*)(ph + r * 72) = (short)hi;
                        *(short*)(pl + r * 72) = (short)f2bf(q - bf2f(hi));
                    }
                } else {                                      // v -> VT[h][d][tok] f16
                    int hh = (ch >> 5) & 3;
                    int d  = ch & 31;
                    h4_t p4 = { (_Float16)vv[0], (_Float16)vv[1],
                                (_Float16)vv[2], (_Float16)vv[3] };
                    *(h4_t*)(PTR(VT_O) + ((hh * 32 + d) * 68 + tokb) * 2) = p4;
                }
            }

    // prefetch w_out + bias into registers (lands during attention phase)
    float4 wo_pref[8];
    #pragma unroll
    for (int it = 0; it < 8; ++it) {
        int idx = t + it * 512;                // 4096 float4
        wo_pref[it] = *(const float4*)(w_out + (size_t)(idx >> 5) * 128 + ((idx & 31) << 2));
    }
    const int mtp2 = wv & 1, ntq2 = wv >> 1;
    float bpref[2];
    bpref[0] = b_out[(2 * ntq2 + 0) * 16 + li];
    bpref[1] = b_out[(2 * ntq2 + 1) * 16 + li];
    __syncthreads();

    // ---------------- per-token norm scales: sq = 50/||q||, sk = 1/||k|| ------
    {
        int qk = t >> 8, hh = (t >> 6) & 3, tok = t & 63;
        const char* bh = PTR(qk ? KH_O : QH_O) + (hh * 64 + tok) * 72;
        const char* bl = PTR(qk ? KL_O : QL_O) + (hh * 64 + tok) * 72;
        float s = 0.f;
        #pragma unroll
        for (int e8 = 0; e8 < 8; ++e8) {
            s4_t a = *(const s4_t*)(bh + e8 * 8);
            s4_t b = *(const s4_t*)(bl + e8 * 8);
            #pragma unroll
            for (int c = 0; c < 4; ++c) {
                float v = bf2f((unsigned short)a[c]) + bf2f((unsigned short)b[c]);
                s += v * v;
            }
        }
        float sc = (qk ? 1.f : 50.f) / fmaxf(sqrtf(s), 1e-12f);
        ((float*)PTR(SCL_O))[qk * 256 + hh * 64 + tok] = sc;
    }
    __syncthreads();

    // ---------------- QK^T + scale + bias + softmax + P + PV (no barriers) ----
    const int hh = wv >> 1;     // head
    const int cc = wv & 1;      // row-half: tokens cc*32 .. +31
    {
        B8 qa[2][2];
        #pragma unroll
        for (int m = 0; m < 2; ++m) {
            int row = (2 * cc + m) * 16 + li;
            const char* bq = PTR(QH_O) + ((hh * 64 + row) * 36 + lg * 8) * 2;
            const char* cq = PTR(QL_O) + ((hh * 64 + row) * 36 + lg * 8) * 2;
            qa[m][0].s[0] = *(const s4_t*)(bq); qa[m][0].s[1] = *(const s4_t*)(bq + 8);
            qa[m][1].s[0] = *(const s4_t*)(cq); qa[m][1].s[1] = *(const s4_t*)(cq + 8);
        }
        f4_t sa[2][4];
        #pragma unroll
        for (int m = 0; m < 2; ++m)
            #pragma unroll
            for (int nt = 0; nt < 4; ++nt) sa[m][nt] = (f4_t){0.f, 0.f, 0.f, 0.f};
        #pragma unroll
        for (int nt = 0; nt < 4; ++nt) {
            int krow = nt * 16 + li;
            const char* bk = PTR(KH_O) + ((hh * 64 + krow) * 36 + lg * 8) * 2;
            const char* ck = PTR(KL_O) + ((hh * 64 + krow) * 36 + lg * 8) * 2;
            B8 kh, kl;
            kh.s[0] = *(const s4_t*)(bk); kh.s[1] = *(const s4_t*)(bk + 8);
            kl.s[0] = *(const s4_t*)(ck); kl.s[1] = *(const s4_t*)(ck + 8);
            #pragma unroll
            for (int m = 0; m < 2; ++m) {
                sa[m][nt] = MFB(qa[m][0].b, kh.b, sa[m][nt]);
                sa[m][nt] = MFB(qa[m][0].b, kl.b, sa[m][nt]);
                sa[m][nt] = MFB(qa[m][1].b, kh.b, sa[m][nt]);
            }
        }

        // rescale by norms, add pos-bias + shift mask, softmax rows, write P (f16)
        const float* scl = (const float*)PTR(SCL_O);
        const float* pef = (const float*)PTR(PE_O);
        float skv[4];
        #pragma unroll
        for (int nt = 0; nt < 4; ++nt) skv[nt] = scl[256 + hh * 64 + nt * 16 + li];
        #pragma unroll
        for (int m = 0; m < 2; ++m)
            #pragma unroll
            for (int r = 0; r < 4; ++r) {
                int i = (2 * cc + m) * 16 + lg * 4 + r;
                float sqv = scl[hh * 64 + i];
                int ri = i >> 3, ci = i & 7;
                float vals[4];
                #pragma unroll
                for (int nt = 0; nt < 4; ++nt) {
                    int col = nt * 16 + li;
                    int rj = col >> 3, cj = col & 7;
                    float bias = pef[(rj - ri + 7) * 15 + (cj - ci + 7)];
                    bool msk = ((wy == 15) && ((i >= 32) != (col >= 32)))
                            || ((wx == 15) && ((ci >= 4) != ((cj & 7) >= 4)));
                    vals[nt] = msk ? -1e30f : (sa[m][nt][r] * sqv * skv[nt] + bias);
                }
                float mx = fmaxf(fmaxf(vals[0], vals[1]), fmaxf(vals[2], vals[3]));
                #pragma unroll
                for (int off = 1; off < 16; off <<= 1) mx = fmaxf(mx, __shfl_xor(mx, off, 16));
                float e0 = __expf(vals[0] - mx), e1 = __expf(vals[1] - mx);
                float e2 = __expf(vals[2] - mx), e3 = __expf(vals[3] - mx);
                float sum = (e0 + e1) + (e2 + e3);
                #pragma unroll
                for (int off = 1; off < 16; off <<= 1) sum += __shfl_xor(sum, off, 16);
                float inv = 1.0f / sum;
                char* prow = PTR(P_O) + ((hh * 64 + i) * 68 + li) * 2;
                *(_Float16*)(prow)      = (_Float16)(e0 * inv);
                *(_Float16*)(prow + 32) = (_Float16)(e1 * inv);
                *(_Float16*)(prow + 64) = (_Float16)(e2 * inv);
                *(_Float16*)(prow + 96) = (_Float16)(e3 * inv);
            }

        // PV (f16): O rows = this wave's own P rows; VT barriered earlier
        f4_t oa[2][2];
        #pragma unroll
        for (int m = 0; m < 2; ++m)
            #pragma unroll
            for (int nv = 0; nv < 2; ++nv) oa[m][nv] = (f4_t){0.f, 0.f, 0.f, 0.f};
        #pragma unroll
        for (int kv = 0; kv < 2; ++kv) {
            B8 pa[2], vb[2];
            #pragma unroll
            for (int m = 0; m < 2; ++m) {
                int row = (2 * cc + m) * 16 + li;
                const char* pp = PTR(P_O) + ((hh * 64 + row) * 68 + kv * 32 + lg * 8) * 2;
                pa[m].s[0] = *(const s4_t*)(pp); pa[m].s[1] = *(const s4_t*)(pp + 8);
            }
            #pragma unroll
            for (int nv = 0; nv < 2; ++nv) {
                int d = nv * 16 + li;
                const char* vp = PTR(VT_O) + ((hh * 32 + d) * 68 + kv * 32 + lg * 8) * 2;
                vb[nv].s[0] = *(const s4_t*)(vp); vb[nv].s[1] = *(const s4_t*)(vp + 8);
            }
            #pragma unroll
            for (int m = 0; m < 2; ++m)
                #pragma unroll
                for (int nv = 0; nv < 2; ++nv)
                    oa[m][nv] = MFH(pa[m].h, vb[nv].h, oa[m][nv]);
        }
        // write O split-bf16 [64][132]
        #pragma unroll
        for (int m = 0; m < 2; ++m)
            #pragma unroll
            for (int nv = 0; nv < 2; ++nv)
                #pragma unroll
                for (int r = 0; r < 4; ++r) {
                    int tokr = (2 * cc + m) * 16 + lg * 4 + r;
                    int d = hh * 32 + nv * 16 + li;
                    float val = oa[m][nv][r];
                    unsigned short hi = f2bf(val);
                    *(short*)(PTR(OH_O) + (tokr * 132 + d) * 2) = (short)hi;
                    *(short*)(PTR(OL_O) + (tokr * 132 + d) * 2) = (short)f2bf(val - bf2f(hi));
                }
    }
    __syncthreads();

    // ---------------- stage w_out (from prefetch regs) over dead Q/K ----------
    #pragma unroll
    for (int it = 0; it < 8; ++it) {
        int idx = t + it * 512;
        int o   = idx >> 5;
        int f4  = (idx & 31) << 2;
        float4 v4 = wo_pref[it];
        unsigned short h0 = f2bf(v4.x), h1 = f2bf(v4.y), h2 = f2bf(v4.z), h3 = f2bf(v4.w);
        s4_t hv = { (short)h0, (short)h1, (short)h2, (short)h3 };
        s4_t lv = { (short)f2bf(v4.x - bf2f(h0)), (short)f2bf(v4.y - bf2f(h1)),
                    (short)f2bf(v4.z - bf2f(h2)), (short)f2bf(v4.w - bf2f(h3)) };
        *(s4_t*)(PTR(WOH_O) + (o * 136 + f4) * 2) = hv;
        *(s4_t*)(PTR(WOL_O) + (o * 136 + f4) * 2) = lv;
    }
    __syncthreads();

    // ---------------- proj: Y = O @ Wout^T + b, reverse shift, store ----------
    {
        f4_t pc[2][2];
        #pragma unroll
        for (int m = 0; m < 2; ++m)
            #pragma unroll
            for (int jj = 0; jj < 2; ++jj) pc[m][jj] = (f4_t){0.f, 0.f, 0.f, 0.f};
        #pragma unroll
        for (int ks = 0; ks < 4; ++ks) {
            int koff = ks * 32 + lg * 8;
            B8 oh[2], ol[2];
            #pragma unroll
            for (int m = 0; m < 2; ++m) {
                int row = (2 * mtp2 + m) * 16 + li;
                const char* po = PTR(OH_O) + (row * 132 + koff) * 2;
                const char* qo = PTR(OL_O) + (row * 132 + koff) * 2;
                oh[m].s[0] = *(const s4_t*)(po); oh[m].s[1] = *(const s4_t*)(po + 8);
                ol[m].s[0] = *(const s4_t*)(qo); ol[m].s[1] = *(const s4_t*)(qo + 8);
            }
            #pragma unroll
            for (int jj = 0; jj < 2; ++jj) {
                int wrow = (2 * ntq2 + jj) * 16 + li;
                bs8 bh = *(const bs8*)(PTR(WOH_O) + (wrow * 136 + koff) * 2);
                bs8 bl = *(const bs8*)(PTR(WOL_O) + (wrow * 136 + koff) * 2);
                #pragma unroll
                for (int m = 0; m < 2; ++m) {
                    pc[m][jj] = MFB(oh[m].b, bh, pc[m][jj]);
                    pc[m][jj] = MFB(oh[m].b, bl, pc[m][jj]);
                    pc[m][jj] = MFB(ol[m].b, bh, pc[m][jj]);
                }
            }
        }
        float* ob = out + (size_t)bi * (IMG * IMG * 128);
        #pragma unroll
        for (int m = 0; m < 2; ++m)
            #pragma unroll
            for (int jj = 0; jj < 2; ++jj) {
                int chn = (2 * ntq2 + jj) * 16 + li;
                float bb = bpref[jj];
                #pragma unroll
                for (int r = 0; r < 4; ++r) {
                    int tokr = (2 * mtp2 + m) * 16 + lg * 4 + r;
                    int gr = ((wy << 3) + (tokr >> 3) + DISP) & 127;
                    int gc = ((wx << 3) + (tokr & 7) + DISP) & 127;
                    ob[(gr * IMG + gc) * 128 + chn] = pc[m][jj][r] + bb;
                }
            }
    }
}

extern "C" void kernel_launch(void* const* d_in, const int* in_sizes, int n_in,
                              void* d_out, int out_size, void* d_ws, size_t ws_size,
                              hipStream_t stream) {
    const float* x       = (const float*)d_in[0];
    const float* w_qkv   = (const float*)d_in[1];
    const float* w_out   = (const float*)d_in[2];
    const float* b_out   = (const float*)d_in[3];
    const float* pos_emb = (const float*)d_in[4];
    float* outp = (float*)d_out;

    swin_window_attn<<<dim3(4096), dim3(512), 0, stream>>>(
        x, w_qkv, w_out, b_out, pos_emb, outp);
}

// Round 3
// 448.571 us; speedup vs baseline: 2.5275x; 1.0748x over previous
//
#include <hip/hip_runtime.h>
#include <math.h>

// Swin shifted-window attention, fully fused, MFMA (split-bf16 + f16 PV).
// Round 3: weights pre-split fp32 -> hi/lo bf16 by a prep kernel into d_ws
// in the exact padded LDS layout, staged via global_load_lds (width 16).
// One block per (batch, window): 4096 blocks x 512 threads (8 waves).
//
// GEMM plan (all MFMA 16x16x32):
//   QKV : C[64][384] = X[64][128] @ Wqkv^T      split-bf16 (3 mfma/tile-k)
//   QK^T: S[64][64]  = Qraw @ Kraw^T  (per head) split-bf16, norms folded in AFTER
//   PV  : O[64][32]  = P @ V          (per head) f16 single
//   proj: Y[64][128] = O[64][128] @ Wout^T       split-bf16

typedef short     bs8 __attribute__((ext_vector_type(8)));   // bf16 frag (4 VGPR)
typedef _Float16  hs8 __attribute__((ext_vector_type(8)));   // f16 frag
typedef float     f4_t __attribute__((ext_vector_type(4)));
typedef short     s4_t __attribute__((ext_vector_type(4)));
typedef _Float16  h4_t __attribute__((ext_vector_type(4)));

union B8 { s4_t s[2]; bs8 b; hs8 h; };

#define MFB(a,b,c) __builtin_amdgcn_mfma_f32_16x16x32_bf16(a,b,c,0,0,0)
#define MFH(a,b,c) __builtin_amdgcn_mfma_f32_16x16x32_f16(a,b,c,0,0,0)

// ---- LDS byte offsets (regions reused across phases; all 16B-aligned) ----
#define XH_O   0
#define XL_O   17408
#define WH_O   34816
#define WL_O   87040      // WH|WL contiguous: [34816, 139264) = 104448 B
#define QH_O   0
#define QL_O   18432
#define KH_O   36864
#define KL_O   55296
#define VT_O   73728
#define P_O    91136
#define OH_O   125952
#define OL_O   142848
#define WOH_O  0
#define WOL_O  34816      // WOH|WOL contiguous: [0, 69632)
#define PE_O   159744
#define SCL_O  160656
#define LDS_BYTES 162704

// ---- d_ws blob (written by prep kernel) ----
// WSQ: 2 halves x (WH 52224 | WL 52224) = 208896 B  (padded rows of 272 B)
// WSO: WOH 34816 | WOL 34816 = 69632 B
#define WSQ_O  0
#define WSO_O  208896

#define IMG 128
#define DISP 4

__device__ __forceinline__ unsigned short f2bf(float f) {
    unsigned u = __float_as_uint(f);
    return (unsigned short)((u + 0x7FFFu + ((u >> 16) & 1u)) >> 16);  // RNE
}
__device__ __forceinline__ float bf2f(unsigned short s) {
    return __uint_as_float(((unsigned)s) << 16);
}
__device__ __forceinline__ void gload16(const void* g, void* l) {
    __builtin_amdgcn_global_load_lds(
        (const __attribute__((address_space(1))) unsigned int*)g,
        (__attribute__((address_space(3))) unsigned int*)l, 16, 0, 0);
}

// ---------------- prep: split weights into padded hi/lo bf16 blob ----------
__global__ __launch_bounds__(256)
void prep_weights(const float* __restrict__ w_qkv,
                  const float* __restrict__ w_out,
                  char* __restrict__ ws)
{
    int idx = blockIdx.x * 256 + threadIdx.x;   // 68*256 = 17408 = 512 rows * 34
    int row = idx / 34;
    int g   = idx - row * 34;
    int e   = g << 2;
    const float* src;
    char *dh, *dl;
    if (row < 384) {
        int hf = row >= 192;
        int r  = row - hf * 192;
        src = w_qkv + (size_t)row * 128;
        dh = ws + WSQ_O + hf * 104448 + r * 272;
        dl = dh + 52224;
    } else {
        int r = row - 384;
        src = w_out + (size_t)r * 128;
        dh = ws + WSO_O + r * 272;
        dl = dh + 34816;
    }
    s4_t hv = {0, 0, 0, 0}, lv = {0, 0, 0, 0};
    if (e < 128) {
        float4 v4 = *(const float4*)(src + e);
        unsigned short h0 = f2bf(v4.x), h1 = f2bf(v4.y), h2 = f2bf(v4.z), h3 = f2bf(v4.w);
        hv = (s4_t){ (short)h0, (short)h1, (short)h2, (short)h3 };
        lv = (s4_t){ (short)f2bf(v4.x - bf2f(h0)), (short)f2bf(v4.y - bf2f(h1)),
                     (short)f2bf(v4.z - bf2f(h2)), (short)f2bf(v4.w - bf2f(h3)) };
    }
    *(s4_t*)(dh + e * 2) = hv;
    *(s4_t*)(dl + e * 2) = lv;
}

__global__ __launch_bounds__(512, 2)
void swin_window_attn(const float* __restrict__ x,
                      const char*  __restrict__ ws,
                      const float* __restrict__ b_out,
                      const float* __restrict__ pos_emb,
                      float* __restrict__ out)
{
    __shared__ __align__(16) char LB[LDS_BYTES];
    #define PTR(off) (LB + (off))

    const int t   = threadIdx.x;
    const int bid = blockIdx.x;
    const int bi  = bid >> 8;
    const int wy  = (bid >> 4) & 15;
    const int wx  = bid & 15;
    const int l   = t & 63;
    const int wv  = t >> 6;
    const int li  = l & 15;
    const int lg  = l >> 4;

    // issue w_qkv half-0 staging first (lands under X conversion)
    {
        const char* wsrc = ws + WSQ_O;            // half 0: 104448 B = 102 chunks
        #pragma unroll
        for (int i = 0; i < 13; ++i) {
            int c = wv + i * 8;
            if (c < 102) gload16(wsrc + c * 1024 + (l << 4), PTR(WH_O) + c * 1024);
        }
    }

    // ---------------- phase 0: stage shifted X window (bf16 hi/lo) + pos_emb ----
    {
        const float* xb = x + (size_t)bi * (IMG * IMG * 128);
        #pragma unroll
        for (int it = 0; it < 4; ++it) {
            int idx = t + it * 512;            // 2048 float4
            int tok = idx >> 5;
            int f4  = (idx & 31) << 2;
            int gr = ((wy << 3) + (tok >> 3) + DISP) & 127;
            int gc = ((wx << 3) + (tok & 7) + DISP) & 127;
            float4 v4 = *(const float4*)(xb + (gr * IMG + gc) * 128 + f4);
            unsigned short h0 = f2bf(v4.x), h1 = f2bf(v4.y), h2 = f2bf(v4.z), h3 = f2bf(v4.w);
            s4_t hv = { (short)h0, (short)h1, (short)h2, (short)h3 };
            s4_t lv = { (short)f2bf(v4.x - bf2f(h0)), (short)f2bf(v4.y - bf2f(h1)),
                        (short)f2bf(v4.z - bf2f(h2)), (short)f2bf(v4.w - bf2f(h3)) };
            *(s4_t*)(PTR(XH_O) + (tok * 136 + f4) * 2) = hv;
            *(s4_t*)(PTR(XL_O) + (tok * 136 + f4) * 2) = lv;
        }
        if (t < 225) ((float*)PTR(PE_O))[t] = pos_emb[t];
    }
    __syncthreads();   // X + W half0 ready (vmcnt drained by syncthreads)

    // ---------------- phase A: QKV = X @ Wqkv^T (two 192-channel halves) -------
    const int mtp = wv >> 2;
    const int ntq = wv & 3;
    f4_t acc[12];
    #pragma unroll
    for (int i = 0; i < 12; ++i) acc[i] = (f4_t){0.f, 0.f, 0.f, 0.f};

    auto gemm_half = [&](int hf) {
        #pragma unroll
        for (int ks = 0; ks < 4; ++ks) {
            int koff = ks * 32 + lg * 8;
            bs8 ah[2], al[2];
            #pragma unroll
            for (int m = 0; m < 2; ++m) {
                int row = ((mtp * 2 + m) * 16 + li);
                ah[m] = *(const bs8*)(PTR(XH_O) + (row * 136 + koff) * 2);
                al[m] = *(const bs8*)(PTR(XL_O) + (row * 136 + koff) * 2);
            }
            #pragma unroll
            for (int j = 0; j < 3; ++j) {
                int wrow = (ntq * 3 + j) * 16 + li;
                bs8 bh = *(const bs8*)(PTR(WH_O) + (wrow * 136 + koff) * 2);
                bs8 bl = *(const bs8*)(PTR(WL_O) + (wrow * 136 + koff) * 2);
                #pragma unroll
                for (int m = 0; m < 2; ++m) {
                    int ai = hf * 6 + j * 2 + m;
                    acc[ai] = MFB(ah[m], bh, acc[ai]);
                    acc[ai] = MFB(ah[m], bl, acc[ai]);
                    acc[ai] = MFB(al[m], bh, acc[ai]);
                }
            }
        }
    };

    gemm_half(0);
    __syncthreads();   // W region free
    {
        const char* wsrc = ws + WSQ_O + 104448;   // half 1
        #pragma unroll
        for (int i = 0; i < 13; ++i) {
            int c = wv + i * 8;
            if (c < 102) gload16(wsrc + c * 1024 + (l << 4), PTR(WH_O) + c * 1024);
        }
    }
    __syncthreads();   // W half1 ready
    gemm_half(1);
    __syncthreads();   // X/W reads done; regions can be overwritten

    // ---------------- distribute QKV: raw-split q/k, f16 V^T -------------------
    #pragma unroll
    for (int hf = 0; hf < 2; ++hf)
        #pragma unroll
        for (int j = 0; j < 3; ++j)
            #pragma unroll
            for (int m = 0; m < 2; ++m) {
                int ch   = hf * 192 + (ntq * 3 + j) * 16 + li;
                int tokb = (mtp * 2 + m) * 16 + lg * 4;
                f4_t vv  = acc[hf * 6 + j * 2 + m];
                if (ch < 256) {                               // q or k (wave-uniform)
                    int isK = ch >> 7;
                    int hh  = (ch >> 5) & 3;
                    int d   = ch & 31;
                    char* ph = PTR(isK ? KH_O : QH_O) + ((hh * 64 + tokb) * 36 + d) * 2;
                    char* pl = PTR(isK ? KL_O : QL_O) + ((hh * 64 + tokb) * 36 + d) * 2;
                    #pragma unroll
                    for (int r = 0; r < 4; ++r) {
                        float q = vv[r];
                        unsigned short hi = f2bf(q);
                        *(short*)(ph + r * 72) = (short)hi;
                        *(short*)(pl + r * 72) = (short)f2bf(q - bf2f(hi));
                    }
                } else {                                      // v -> VT[h][d][tok] f16
                    int hh = (ch >> 5) & 3;
                    int d  = ch & 31;
                    h4_t p4 = { (_Float16)vv[0], (_Float16)vv[1],
                                (_Float16)vv[2], (_Float16)vv[3] };
                    *(h4_t*)(PTR(VT_O) + ((hh * 32 + d) * 68 + tokb) * 2) = p4;
                }
            }

    const int mtp2 = wv & 1, ntq2 = wv >> 1;
    float bpref[2];
    bpref[0] = b_out[(2 * ntq2 + 0) * 16 + li];
    bpref[1] = b_out[(2 * ntq2 + 1) * 16 + li];
    __syncthreads();

    // ---------------- per-token norm scales: sq = 50/||q||, sk = 1/||k|| ------
    {
        int qk = t >> 8, hh = (t >> 6) & 3, tok = t & 63;
        const char* bh = PTR(qk ? KH_O : QH_O) + (hh * 64 + tok) * 72;
        const char* bl = PTR(qk ? KL_O : QL_O) + (hh * 64 + tok) * 72;
        float s = 0.f;
        #pragma unroll
        for (int e8 = 0; e8 < 8; ++e8) {
            s4_t a = *(const s4_t*)(bh + e8 * 8);
            s4_t b = *(const s4_t*)(bl + e8 * 8);
            #pragma unroll
            for (int c = 0; c < 4; ++c) {
                float v = bf2f((unsigned short)a[c]) + bf2f((unsigned short)b[c]);
                s += v * v;
            }
        }
        float sc = (qk ? 1.f : 50.f) / fmaxf(sqrtf(s), 1e-12f);
        ((float*)PTR(SCL_O))[qk * 256 + hh * 64 + tok] = sc;
    }
    __syncthreads();

    // ---------------- QK^T ----------------------------------------------------
    const int hh = wv >> 1;     // head
    const int cc = wv & 1;      // row-half: tokens cc*32 .. +31
    f4_t sa[2][4];
    {
        B8 qa[2][2];
        #pragma unroll
        for (int m = 0; m < 2; ++m) {
            int row = (2 * cc + m) * 16 + li;
            const char* bq = PTR(QH_O) + ((hh * 64 + row) * 36 + lg * 8) * 2;
            const char* cq = PTR(QL_O) + ((hh * 64 + row) * 36 + lg * 8) * 2;
            qa[m][0].s[0] = *(const s4_t*)(bq); qa[m][0].s[1] = *(const s4_t*)(bq + 8);
            qa[m][1].s[0] = *(const s4_t*)(cq); qa[m][1].s[1] = *(const s4_t*)(cq + 8);
        }
        #pragma unroll
        for (int m = 0; m < 2; ++m)
            #pragma unroll
            for (int nt = 0; nt < 4; ++nt) sa[m][nt] = (f4_t){0.f, 0.f, 0.f, 0.f};
        #pragma unroll
        for (int nt = 0; nt < 4; ++nt) {
            int krow = nt * 16 + li;
            const char* bk = PTR(KH_O) + ((hh * 64 + krow) * 36 + lg * 8) * 2;
            const char* ck = PTR(KL_O) + ((hh * 64 + krow) * 36 + lg * 8) * 2;
            B8 kh, kl;
            kh.s[0] = *(const s4_t*)(bk); kh.s[1] = *(const s4_t*)(bk + 8);
            kl.s[0] = *(const s4_t*)(ck); kl.s[1] = *(const s4_t*)(ck + 8);
            #pragma unroll
            for (int m = 0; m < 2; ++m) {
                sa[m][nt] = MFB(qa[m][0].b, kh.b, sa[m][nt]);
                sa[m][nt] = MFB(qa[m][0].b, kl.b, sa[m][nt]);
                sa[m][nt] = MFB(qa[m][1].b, kh.b, sa[m][nt]);
            }
        }
    }
    __syncthreads();   // Q/K LDS dead for ALL waves

    // issue w_out staging now -> latency hides under softmax + PV
    {
        const char* wsrc = ws + WSO_O;            // 69632 B = 68 chunks
        #pragma unroll
        for (int i = 0; i < 9; ++i) {
            int c = wv + i * 8;
            if (c < 68) gload16(wsrc + c * 1024 + (l << 4), PTR(WOH_O) + c * 1024);
        }
    }

    // ---------------- softmax + P + PV ----------------------------------------
    {
        const float* scl = (const float*)PTR(SCL_O);
        const float* pef = (const float*)PTR(PE_O);
        float skv[4];
        #pragma unroll
        for (int nt = 0; nt < 4; ++nt) skv[nt] = scl[256 + hh * 64 + nt * 16 + li];
        #pragma unroll
        for (int m = 0; m < 2; ++m)
            #pragma unroll
            for (int r = 0; r < 4; ++r) {
                int i = (2 * cc + m) * 16 + lg * 4 + r;
                float sqv = scl[hh * 64 + i];
                int ri = i >> 3, ci = i & 7;
                float vals[4];
                #pragma unroll
                for (int nt = 0; nt < 4; ++nt) {
                    int col = nt * 16 + li;
                    int rj = col >> 3, cj = col & 7;
                    float bias = pef[(rj - ri + 7) * 15 + (cj - ci + 7)];
                    bool msk = ((wy == 15) && ((i >= 32) != (col >= 32)))
                            || ((wx == 15) && ((ci >= 4) != ((cj & 7) >= 4)));
                    vals[nt] = msk ? -1e30f : (sa[m][nt][r] * sqv * skv[nt] + bias);
                }
                float mx = fmaxf(fmaxf(vals[0], vals[1]), fmaxf(vals[2], vals[3]));
                #pragma unroll
                for (int off = 1; off < 16; off <<= 1) mx = fmaxf(mx, __shfl_xor(mx, off, 16));
                float e0 = __expf(vals[0] - mx), e1 = __expf(vals[1] - mx);
                float e2 = __expf(vals[2] - mx), e3 = __expf(vals[3] - mx);
                float sum = (e0 + e1) + (e2 + e3);
                #pragma unroll
                for (int off = 1; off < 16; off <<= 1) sum += __shfl_xor(sum, off, 16);
                float inv = 1.0f / sum;
                char* prow = PTR(P_O) + ((hh * 64 + i) * 68 + li) * 2;
                *(_Float16*)(prow)      = (_Float16)(e0 * inv);
                *(_Float16*)(prow + 32) = (_Float16)(e1 * inv);
                *(_Float16*)(prow + 64) = (_Float16)(e2 * inv);
                *(_Float16*)(prow + 96) = (_Float16)(e3 * inv);
            }

        // PV (f16): O rows = this wave's own P rows (within-wave dependency only)
        f4_t oa[2][2];
        #pragma unroll
        for (int m = 0; m < 2; ++m)
            #pragma unroll
            for (int nv = 0; nv < 2; ++nv) oa[m][nv] = (f4_t){0.f, 0.f, 0.f, 0.f};
        #pragma unroll
        for (int kv = 0; kv < 2; ++kv) {
            B8 pa[2], vb[2];
            #pragma unroll
            for (int m = 0; m < 2; ++m) {
                int row = (2 * cc + m) * 16 + li;
                const char* pp = PTR(P_O) + ((hh * 64 + row) * 68 + kv * 32 + lg * 8) * 2;
                pa[m].s[0] = *(const s4_t*)(pp); pa[m].s[1] = *(const s4_t*)(pp + 8);
            }
            #pragma unroll
            for (int nv = 0; nv < 2; ++nv) {
                int d = nv * 16 + li;
                const char* vp = PTR(VT_O) + ((hh * 32 + d) * 68 + kv * 32 + lg * 8) * 2;
                vb[nv].s[0] = *(const s4_t*)(vp); vb[nv].s[1] = *(const s4_t*)(vp + 8);
            }
            #pragma unroll
            for (int m = 0; m < 2; ++m)
                #pragma unroll
                for (int nv = 0; nv < 2; ++nv)
                    oa[m][nv] = MFH(pa[m].h, vb[nv].h, oa[m][nv]);
        }
        // write O split-bf16 [64][132]
        #pragma unroll
        for (int m = 0; m < 2; ++m)
            #pragma unroll
            for (int nv = 0; nv < 2; ++nv)
                #pragma unroll
                for (int r = 0; r < 4; ++r) {
                    int tokr = (2 * cc + m) * 16 + lg * 4 + r;
                    int d = hh * 32 + nv * 16 + li;
                    float val = oa[m][nv][r];
                    unsigned short hi = f2bf(val);
                    *(short*)(PTR(OH_O) + (tokr * 132 + d) * 2) = (short)hi;
                    *(short*)(PTR(OL_O) + (tokr * 132 + d) * 2) = (short)f2bf(val - bf2f(hi));
                }
    }
    __syncthreads();   // O written; w_out staging landed (vmcnt drained)

    // ---------------- proj: Y = O @ Wout^T + b, reverse shift, store ----------
    {
        f4_t pc[2][2];
        #pragma unroll
        for (int m = 0; m < 2; ++m)
            #pragma unroll
            for (int jj = 0; jj < 2; ++jj) pc[m][jj] = (f4_t){0.f, 0.f, 0.f, 0.f};
        #pragma unroll
        for (int ks = 0; ks < 4; ++ks) {
            int koff = ks * 32 + lg * 8;
            B8 oh[2], ol[2];
            #pragma unroll
            for (int m = 0; m < 2; ++m) {
                int row = (2 * mtp2 + m) * 16 + li;
                const char* po = PTR(OH_O) + (row * 132 + koff) * 2;
                const char* qo = PTR(OL_O) + (row * 132 + koff) * 2;
                oh[m].s[0] = *(const s4_t*)(po); oh[m].s[1] = *(const s4_t*)(po + 8);
                ol[m].s[0] = *(const s4_t*)(qo); ol[m].s[1] = *(const s4_t*)(qo + 8);
            }
            #pragma unroll
            for (int jj = 0; jj < 2; ++jj) {
                int wrow = (2 * ntq2 + jj) * 16 + li;
                bs8 bh = *(const bs8*)(PTR(WOH_O) + (wrow * 136 + koff) * 2);
                bs8 bl = *(const bs8*)(PTR(WOL_O) + (wrow * 136 + koff) * 2);
                #pragma unroll
                for (int m = 0; m < 2; ++m) {
                    pc[m][jj] = MFB(oh[m].b, bh, pc[m][jj]);
                    pc[m][jj] = MFB(oh[m].b, bl, pc[m][jj]);
                    pc[m][jj] = MFB(ol[m].b, bh, pc[m][jj]);
                }
            }
        }
        float* ob = out + (size_t)bi * (IMG * IMG * 128);
        #pragma unroll
        for (int m = 0; m < 2; ++m)
            #pragma unroll
            for (int jj = 0; jj < 2; ++jj) {
                int chn = (2 * ntq2 + jj) * 16 + li;
                float bb = bpref[jj];
                #pragma unroll
                for (int r = 0; r < 4; ++r) {
                    int tokr = (2 * mtp2 + m) * 16 + lg * 4 + r;
                    int gr = ((wy << 3) + (tokr >> 3) + DISP) & 127;
                    int gc = ((wx << 3) + (tokr & 7) + DISP) & 127;
                    ob[(gr * IMG + gc) * 128 + chn] = pc[m][jj][r] + bb;
                }
            }
    }
}

extern "C" void kernel_launch(void* const* d_in, const int* in_sizes, int n_in,
                              void* d_out, int out_size, void* d_ws, size_t ws_size,
                              hipStream_t stream) {
    const float* x       = (const float*)d_in[0];
    const float* w_qkv   = (const float*)d_in[1];
    const float* w_out   = (const float*)d_in[2];
    const float* b_out   = (const float*)d_in[3];
    const float* pos_emb = (const float*)d_in[4];
    float* outp = (float*)d_out;
    char* ws = (char*)d_ws;

    prep_weights<<<dim3(68), dim3(256), 0, stream>>>(w_qkv, w_out, ws);
    swin_window_attn<<<dim3(4096), dim3(512), 0, stream>>>(
        x, ws, b_out, pos_emb, outp);
}